// Round 20
// baseline (563.389 us; speedup 1.0000x reference)
//
#include <hip/hip_runtime.h>
#include <stdint.h>

typedef unsigned short u16;
typedef unsigned int   u32;
typedef _Float16 f16x8 __attribute__((ext_vector_type(8)));
typedef __attribute__((ext_vector_type(16))) float f16v;

#define JJ 17
#define CC 128
#define BB 7
#define ROWS (BB*JJ)     // 119
#define PP 128
#define XP 132           // xh pitch (u16): 264B rows, b64 frags, 2-bank stride
#define HTP 140          // h1t pitch (u16): 280B cols, b64-aligned, 16-bank spread
#define NLAYERS 5
#define NT 512

#define DIAG_OFF 35840                  // alias region: max(xh 33792B, h1t 35840B)
#define LDS_BYTES (DIAG_OFF + 512)      // 36352 < 64K -> multi-block/CU

#define MFMA __builtin_amdgcn_mfma_f32_32x32x16_f16

__device__ __forceinline__ u16 h2b(_Float16 h) {
  union { _Float16 h; u16 b; } c; c.h = h; return c.b;
}
__device__ __forceinline__ _Float16 b2h(u16 b) {
  union { u16 b; _Float16 h; } c; c.b = b; return c.h;
}
__device__ __forceinline__ float wred(float v) {
  #pragma unroll
  for (int m = 32; m >= 1; m >>= 1) v += __shfl_xor(v, m, 64);
  return v;
}
__device__ __forceinline__ f16x8 u4f8(uint4 v) {
  union { uint4 u; f16x8 f; } c; c.u = v; return c.f;
}
__device__ __forceinline__ f16x8 mk8(uint2 a, uint2 b) {
  union { uint4 u; f16x8 f; } c;
  c.u.x = a.x; c.u.y = a.y; c.u.z = b.x; c.u.w = b.y;
  return c.f;
}

// ---- setup: W->f16 frag layout [w][col][k]; Amix MFMA A-frags [t][i][g][nl][8]
__global__ void __launch_bounds__(256)
wprep(const float* __restrict__ W0, const float* __restrict__ W1,
      const float* __restrict__ adj, u16* __restrict__ wsH,
      u16* __restrict__ amixf)
{
  __shared__ float wt[64*130];
  const int w01 = blockIdx.x;
  const float* Wp = w01 ? W1 : W0;
  const int tid = threadIdx.x;
  if (w01 == 0) {
    for (int t = tid; t < 8192; t += 256) {
      int e  = t & 7, nl = (t >> 3) & 31, g = (t >> 8) & 1;
      int i  = (t >> 9) & 3, tt = t >> 11;           // tile 0..3
      const int kslo = (tt==0)?0:(tt==1)?1:(tt==2)?3:4;
      int row = tt*32 + nl;
      int k   = (kslo + i)*16 + 8*g + e;
      float v = 0.f;
      if (row < ROWS && k < ROWS && (row/JJ) == (k/JJ) && (row%JJ) != (k%JJ))
        v = 0.8f * adj[(row%JJ)*JJ + (k%JJ)];
      amixf[t] = h2b((_Float16)v);
    }
  }
  for (int kh = 0; kh < 2; ++kh) {
    if (kh) __syncthreads();
    #pragma unroll
    for (int i = 0; i < 32; ++i) {
      int idx = tid + i*256;           // [64 kk][128 col] coalesced read
      int kk = idx >> 7, col = idx & 127;
      wt[kk*130 + col] = Wp[(kh*64 + kk)*128 + col];
    }
    __syncthreads();
    #pragma unroll
    for (int i = 0; i < 32; ++i) {
      int idx = tid + i*256;           // [128 col][64 kk] coalesced write
      int col = idx >> 6, kk = idx & 63;
      wsH[(size_t)(w01*128 + col)*128 + kh*64 + kk] = h2b((_Float16)wt[kk*130 + col]);
    }
  }
}

__global__ void __launch_bounds__(NT, 4)
gconv_fused(const float* __restrict__ x, const float* __restrict__ x0,
            const float* __restrict__ adj, const u16* __restrict__ wsH,
            const u16* __restrict__ amixf, const float* __restrict__ bvec,
            const float* __restrict__ gamma, const float* __restrict__ beta,
            float* __restrict__ out, int totRows)
{
  extern __shared__ char smem[];
  u16*   xh    = (u16*)smem;                // [128][132] x (f16)  — aliases h1t
  u16*   h1t   = (u16*)smem;                // [128 col][140] f16 H1^T — alias
  float* diag8 = (float*)(smem + DIAG_OFF); // [128]

  const int tid  = threadIdx.x;
  const int lane = tid & 63;
  const int wid  = tid >> 6;        // 0..7
  const int wm   = wid >> 2;        // 0..1  (M half: 64 rows)
  const int wn   = wid & 3;         // 0..3  (N tile)
  const int g    = lane >> 5;
  const int nl   = lane & 31;
  const int ccol = wn*32 + nl;
  const int grow0 = blockIdx.x * ROWS;

  // ---- x0 (pre-scaled by 0.2) -> packed f16 regs, accumulator layout
  u32 x0p[2][8];
  #pragma unroll
  for (int mt = 0; mt < 2; ++mt)
    #pragma unroll
    for (int qp = 0; qp < 8; ++qp) {
      u32 pk = 0;
      #pragma unroll
      for (int h = 0; h < 2; ++h) {
        int q = qp*2 + h;
        int row = wm*64 + mt*32 + (q&3) + 8*(q>>2) + 4*g;
        int grow = grow0 + row;
        u16 bits = 0;
        if (row < ROWS && grow < totRows)
          bits = h2b((_Float16)(0.2f * x0[(size_t)grow*CC + ccol]));
        pk |= ((u32)bits) << (16*h);
      }
      x0p[mt][qp] = pk;
    }
  const float bias_c = bvec[ccol];

  // ---- x -> xh f16 plane; pad rows zero
  #pragma unroll
  for (int i = 0; i < 8; ++i) {
    int el4 = tid + i*NT;              // 4096 float4 = 128 rows x 128
    int r = el4 >> 5, c4 = (el4 & 31) << 2;
    float4 v = make_float4(0.f, 0.f, 0.f, 0.f);
    if (r < ROWS && (grow0 + r) < totRows)
      v = *(const float4*)&x[(size_t)(grow0 + r)*CC + c4];
    u16 s0 = h2b((_Float16)v.x), s1 = h2b((_Float16)v.y);
    u16 s2 = h2b((_Float16)v.z), s3 = h2b((_Float16)v.w);
    *(uint2*)&xh[r*XP + c4] = make_uint2((u32)s0 | ((u32)s1<<16), (u32)s2 | ((u32)s3<<16));
  }
  if (tid < PP) {
    int j = tid % JJ;
    diag8[tid] = (tid < ROWS) ? 0.8f * adj[j*JJ + j] : 0.f;
  }
  __syncthreads();

  const u16* w0p = wsH + (size_t)ccol*128 + 8*g;          // W0 frag col base
  const u16* w1p = wsH + (size_t)(128 + ccol)*128 + 8*g;  // W1

  // ================= layer loop (4 barriers; W/amix from L2) =================
  #pragma unroll 1
  for (int layer = 0; layer < NLAYERS; ++layer) {
    f16v acc0[2], acc1[2];
    #pragma unroll
    for (int mt = 0; mt < 2; ++mt)
      #pragma unroll
      for (int i = 0; i < 16; ++i) { acc0[mt][i] = 0.f; acc1[mt][i] = 0.f; }

    // ---- GEMM: A from LDS (b64 pairs), W from global with prefetch-1
    f16x8 b0 = u4f8(*(const uint4*)(w0p));
    f16x8 b1 = u4f8(*(const uint4*)(w1p));
    #pragma unroll
    for (int ks = 0; ks < 8; ++ks) {
      f16x8 nb0 = b0, nb1 = b1;
      if (ks < 7) {
        nb0 = u4f8(*(const uint4*)(w0p + (ks+1)*16));
        nb1 = u4f8(*(const uint4*)(w1p + (ks+1)*16));
      }
      #pragma unroll
      for (int mt = 0; mt < 2; ++mt) {
        const int xb = (wm*64 + mt*32 + nl)*XP + ks*16 + 8*g;
        f16x8 ah = mk8(*(const uint2*)&xh[xb], *(const uint2*)&xh[xb+4]);
        acc0[mt] = MFMA(ah, b0, acc0[mt], 0, 0, 0);
        acc1[mt] = MFMA(ah, b1, acc1[mt], 0, 0, 0);
      }
      __builtin_amdgcn_sched_barrier(0);   // cap liveness; keep prefetch placed
      b0 = nb0; b1 = nb1;
    }
    __syncthreads();   // (1) all xh reads done (h1t aliases xh)

    // ---- epilogue: acc1 (X@W1) -> h1t transposed, f16 pairs
    #pragma unroll
    for (int mt = 0; mt < 2; ++mt)
      #pragma unroll
      for (int qp = 0; qp < 8; ++qp) {
        int q = qp*2;
        int row = wm*64 + mt*32 + (q&3) + 8*(q>>2) + 4*g;   // even
        u32 pk = (u32)h2b((_Float16)acc1[mt][q]) | ((u32)h2b((_Float16)acc1[mt][q+1]) << 16);
        *(u32*)&h1t[ccol*HTP + row] = pk;
      }
    __syncthreads();   // (2) h1t complete

    // ---- mix GEMM: acc1 (reused) = Amix * H1 per mt; 4 MFMAs each
    #pragma unroll
    for (int mt = 0; mt < 2; ++mt) {
      const int t = wm*2 + mt;
      const int kslo = (t==0)?0:(t==1)?1:(t==2)?3:4;
      f16x8 am[4];
      #pragma unroll
      for (int i = 0; i < 4; ++i)
        am[i] = u4f8(*(const uint4*)&amixf[(((t*4+i)*2)+g)*256 + nl*8]);
      #pragma unroll
      for (int i = 0; i < 16; ++i) acc1[mt][i] = 0.f;
      #pragma unroll
      for (int i = 0; i < 4; ++i) {
        const int hidx = ccol*HTP + (kslo + i)*16 + 8*g;
        f16x8 hb = mk8(*(const uint2*)&h1t[hidx], *(const uint2*)&h1t[hidx+4]);
        acc1[mt] = MFMA(am[i], hb, acc1[mt], 0, 0, 0);
      }
    }
    __syncthreads();   // (3) all h1t reads done before xh overwrite

    // ---- combine: x' = 0.2x0 + diag*acc0 + mix + b -> xh (f16)
    #pragma unroll
    for (int mt = 0; mt < 2; ++mt)
      #pragma unroll
      for (int q = 0; q < 16; ++q) {
        int row = wm*64 + mt*32 + (q&3) + 8*(q>>2) + 4*g;
        float x0v = (float)b2h((u16)(x0p[mt][q>>1] >> (16*(q&1))));
        float v = x0v + diag8[row]*acc0[mt][q] + acc1[mt][q] + bias_c;
        xh[row*XP + ccol] = h2b((_Float16)v);
      }
    __syncthreads();   // (4) xh ready for next layer / LN
  }

  // ---- LayerNorm + store (reads f16 xh), 8 waves
  float ga = gamma[lane], g2 = gamma[64+lane];
  float ba = beta[lane],  b2f = beta[64+lane];
  #pragma unroll 1
  for (int i = 0; i < 16; ++i) {
    int r = wid + 8*i;             // wave-uniform, 0..127
    if (r >= ROWS) continue;
    int grow = grow0 + r;
    if (grow >= totRows) continue;
    float xa = (float)b2h(xh[r*XP + lane]);
    float xc = (float)b2h(xh[r*XP + 64 + lane]);
    float mu = wred(xa + xc) * (1.f/128.f);
    float da = xa - mu, dc = xc - mu;
    float vs = wred(da*da + dc*dc) * (1.f/128.f);
    float rs = rsqrtf(vs + 1e-10f);
    size_t ob = (size_t)grow*CC;
    out[ob + lane]      = da*rs*ga + ba;
    out[ob + 64 + lane] = dc*rs*g2 + b2f;
  }
}

extern "C" void kernel_launch(void* const* d_in, const int* in_sizes, int n_in,
                              void* d_out, int out_size, void* d_ws, size_t ws_size,
                              hipStream_t stream) {
  const float* x   = (const float*)d_in[0];
  const float* x0  = (const float*)d_in[1];
  const float* adj = (const float*)d_in[2];
  const float* W0  = (const float*)d_in[3];
  const float* W1  = (const float*)d_in[4];
  const float* bv  = (const float*)d_in[5];
  const float* ga  = (const float*)d_in[6];
  const float* be  = (const float*)d_in[7];
  u16* wsH   = (u16*)d_ws;                      // [2][128][128] f16 = 65536 B
  u16* amixf = (u16*)((char*)d_ws + 65536);     // [4][4][2][32][8] f16 = 16384 B
  int totRows = in_sizes[0] / CC;
  int nBatch  = totRows / JJ;
  int grid    = (nBatch + BB - 1) / BB;
  wprep<<<dim3(2), dim3(256), 0, stream>>>(W0, W1, adj, wsH, amixf);
  gconv_fused<<<dim3(grid), dim3(NT), LDS_BYTES, stream>>>(
      x, x0, adj, wsH, amixf, bv, ga, be, (float*)d_out, totRows);
}

// Round 21
// 374.098 us; speedup vs baseline: 1.5060x; 1.5060x over previous
//
#include <hip/hip_runtime.h>
#include <stdint.h>

typedef unsigned short u16;
typedef unsigned int   u32;
typedef _Float16 f16x8 __attribute__((ext_vector_type(8)));
typedef __attribute__((ext_vector_type(16))) float f16v;

#define JJ 17
#define CC 128
#define BB 7
#define ROWS (BB*JJ)     // 119
#define PP 128
#define XP 132           // xh pitch (u16): 264B rows, b64 frags, 2-bank stride (free)
#define HTP 140          // h1t pitch (u16): 280B -> 70dw stride, 2-way bank (free)
#define NLAYERS 5
#define NT 1024

#define XH_OFF   0                        // xh  [128][132] u16 = 33792
#define HT_OFF   33792                    // h1t [128][140] u16 = 35840 -> 69632
#define W_OFF    69632                    // wlds[2][128][132] u16 = 67584 -> 137216
#define DIAG_OFF 137216                   // [128] f32 = 512
#define LDS_BYTES (DIAG_OFF + 512)        // 137728 -> 1 block/CU, 16 waves (4/SIMD)

#define MFMA __builtin_amdgcn_mfma_f32_32x32x16_f16

__device__ __forceinline__ u16 h2b(_Float16 h) {
  union { _Float16 h; u16 b; } c; c.h = h; return c.b;
}
__device__ __forceinline__ _Float16 b2h(u16 b) {
  union { u16 b; _Float16 h; } c; c.b = b; return c.h;
}
__device__ __forceinline__ float wred(float v) {
  #pragma unroll
  for (int m = 32; m >= 1; m >>= 1) v += __shfl_xor(v, m, 64);
  return v;
}
__device__ __forceinline__ f16x8 u4f8(uint4 v) {
  union { uint4 u; f16x8 f; } c; c.u = v; return c.f;
}
__device__ __forceinline__ f16x8 mk8(uint2 a, uint2 b) {
  union { uint4 u; f16x8 f; } c;
  c.u.x = a.x; c.u.y = a.y; c.u.z = b.x; c.u.w = b.y;
  return c.f;
}

// ---- setup: W->f16 frag layout [w][col][k]; Amix MFMA A-frags [t][i][g][nl][8]
__global__ void __launch_bounds__(256)
wprep(const float* __restrict__ W0, const float* __restrict__ W1,
      const float* __restrict__ adj, u16* __restrict__ wsH,
      u16* __restrict__ amixf)
{
  __shared__ float wt[64*130];
  const int w01 = blockIdx.x;
  const float* Wp = w01 ? W1 : W0;
  const int tid = threadIdx.x;
  if (w01 == 0) {
    for (int t = tid; t < 8192; t += 256) {
      int e  = t & 7, nl = (t >> 3) & 31, g = (t >> 8) & 1;
      int i  = (t >> 9) & 3, tt = t >> 11;           // tile 0..3
      const int kslo = (tt==0)?0:(tt==1)?1:(tt==2)?3:4;
      int row = tt*32 + nl;
      int k   = (kslo + i)*16 + 8*g + e;
      float v = 0.f;
      if (row < ROWS && k < ROWS && (row/JJ) == (k/JJ) && (row%JJ) != (k%JJ))
        v = 0.8f * adj[(row%JJ)*JJ + (k%JJ)];
      amixf[t] = h2b((_Float16)v);
    }
  }
  for (int kh = 0; kh < 2; ++kh) {
    if (kh) __syncthreads();
    #pragma unroll
    for (int i = 0; i < 32; ++i) {
      int idx = tid + i*256;           // [64 kk][128 col] coalesced read
      int kk = idx >> 7, col = idx & 127;
      wt[kk*130 + col] = Wp[(kh*64 + kk)*128 + col];
    }
    __syncthreads();
    #pragma unroll
    for (int i = 0; i < 32; ++i) {
      int idx = tid + i*256;           // [128 col][64 kk] coalesced write
      int col = idx >> 6, kk = idx & 63;
      wsH[(size_t)(w01*128 + col)*128 + kh*64 + kk] = h2b((_Float16)wt[kk*130 + col]);
    }
  }
}

__global__ void __launch_bounds__(NT, 4)
gconv_fused(const float* __restrict__ x, const float* __restrict__ x0,
            const float* __restrict__ adj, const u16* __restrict__ wsH,
            const u16* __restrict__ amixf, const float* __restrict__ bvec,
            const float* __restrict__ gamma, const float* __restrict__ beta,
            float* __restrict__ out, int totRows)
{
  extern __shared__ char smem[];
  u16*   xh    = (u16*)(smem + XH_OFF);    // [128][132] x (f16)
  u16*   h1t   = (u16*)(smem + HT_OFF);    // [128 col][140] f16 H1^T
  u16*   wlds  = (u16*)(smem + W_OFF);     // [2][128][132] f16 W frag layout
  float* diag8 = (float*)(smem + DIAG_OFF);// [128]

  const int tid  = threadIdx.x;
  const int lane = tid & 63;
  const int wid  = tid >> 6;        // 0..15
  const int wm   = wid >> 2;        // 0..3  M-tile (32 rows)
  const int wn   = wid & 3;         // 0..3  N-tile (32 cols)
  const int g    = lane >> 5;
  const int nl   = lane & 31;
  const int ccol = wn*32 + nl;
  const int grow0 = blockIdx.x * ROWS;
  const int kslo = (wm==0)?0:(wm==1)?1:(wm==2)?3:4;

  // ---- W (f16) -> LDS: 32 contiguous u16/thread, 8B writes
  {
    int el = tid * 32;                 // 0..32767
    int w01 = el >> 14, rem = el & 16383;
    int col = rem >> 7, k0 = rem & 127;
    const u16* src = wsH + el;
    u16* dst = &wlds[(w01*128 + col)*XP + k0];
    #pragma unroll
    for (int c = 0; c < 8; ++c)
      *(uint2*)(dst + c*4) = *(const uint2*)(src + c*4);
  }

  // ---- x0 (pre-scaled 0.2) -> 8 packed-f16 regs, accumulator layout
  u32 x0p[8];
  #pragma unroll
  for (int qp = 0; qp < 8; ++qp) {
    u32 pk = 0;
    #pragma unroll
    for (int h = 0; h < 2; ++h) {
      int q = qp*2 + h;
      int row = wm*32 + (q&3) + 8*(q>>2) + 4*g;
      int grow = grow0 + row;
      u16 bits = 0;
      if (row < ROWS && grow < totRows)
        bits = h2b((_Float16)(0.2f * x0[(size_t)grow*CC + ccol]));
      pk |= ((u32)bits) << (16*h);
    }
    x0p[qp] = pk;
  }
  const float bias_c = bvec[ccol];

  // ---- x -> xh f16 plane (float4 in); pad rows zero
  #pragma unroll
  for (int i = 0; i < 4; ++i) {
    int el4 = tid + i*NT;              // 4096 float4 = 128 rows x 128
    int r = el4 >> 5, c4 = (el4 & 31) << 2;
    float4 v = make_float4(0.f, 0.f, 0.f, 0.f);
    if (r < ROWS && (grow0 + r) < totRows)
      v = *(const float4*)&x[(size_t)(grow0 + r)*CC + c4];
    u16 s0 = h2b((_Float16)v.x), s1 = h2b((_Float16)v.y);
    u16 s2 = h2b((_Float16)v.z), s3 = h2b((_Float16)v.w);
    *(uint2*)&xh[r*XP + c4] = make_uint2((u32)s0 | ((u32)s1<<16), (u32)s2 | ((u32)s3<<16));
  }
  if (tid >= 512 && tid < 512 + PP) {
    int t = tid - 512;
    int j = t % JJ;
    diag8[t] = (t < ROWS) ? 0.8f * adj[j*JJ + j] : 0.f;
  }
  __syncthreads();

  const int arow = (wm*32 + nl)*XP;            // A base (+= ks*16 + 8g)
  const int bb0  = ccol*XP;                    // W0 frag base
  const int bb1  = bb0 + 128*XP;               // W1
  const u16* amp = amixf + ((wm*4*2) + g)*256 + nl*8;   // +i*512 per frag

  // ================= layer loop (2 barriers; no spill) =================
  #pragma unroll 1
  for (int layer = 0; layer < NLAYERS; ++layer) {
    f16v acc0, acc1;
    #pragma unroll
    for (int i = 0; i < 16; ++i) { acc0[i] = 0.f; acc1[i] = 0.f; }

    // ---- GEMM: per ks: 6 b64 reads + 2 MFMA
    #pragma unroll
    for (int ks = 0; ks < 8; ++ks) {
      const int o = ks*16 + 8*g;
      f16x8 ah = mk8(*(const uint2*)&xh[arow + o],  *(const uint2*)&xh[arow + o + 4]);
      f16x8 b0 = mk8(*(const uint2*)&wlds[bb0 + o], *(const uint2*)&wlds[bb0 + o + 4]);
      f16x8 b1 = mk8(*(const uint2*)&wlds[bb1 + o], *(const uint2*)&wlds[bb1 + o + 4]);
      acc0 = MFMA(ah, b0, acc0, 0, 0, 0);
      acc1 = MFMA(ah, b1, acc1, 0, 0, 0);
      __builtin_amdgcn_sched_barrier(0);   // cap fragment liveness per K-step
    }

    // ---- epilogue: acc1 (X@W1) -> h1t transposed, f16 pairs (8 u32 writes)
    #pragma unroll
    for (int qp = 0; qp < 8; ++qp) {
      int q = qp*2;
      int row = wm*32 + (q&3) + 8*(q>>2) + 4*g;      // even; row+1 is q+1
      u32 pk = (u32)h2b((_Float16)acc1[q]) | ((u32)h2b((_Float16)acc1[q+1]) << 16);
      *(u32*)&h1t[ccol*HTP + row] = pk;
    }
    __syncthreads();   // (1) h1t complete; all xh GEMM reads done

    // ---- mix GEMM: acc1 (reused) = Amix * H1; amix frags from L1-hot global
    #pragma unroll
    for (int i = 0; i < 16; ++i) acc1[i] = 0.f;
    #pragma unroll
    for (int i = 0; i < 4; ++i) {
      f16x8 am = u4f8(*(const uint4*)(amp + i*512));
      const int hidx = ccol*HTP + (kslo + i)*16 + 8*g;
      f16x8 hb = mk8(*(const uint2*)&h1t[hidx], *(const uint2*)&h1t[hidx+4]);
      acc1 = MFMA(am, hb, acc1, 0, 0, 0);
    }

    // ---- combine: x' = 0.2x0 + diag*acc0 + mix + b -> xh (f16)
    #pragma unroll
    for (int q = 0; q < 16; ++q) {
      int row = wm*32 + (q&3) + 8*(q>>2) + 4*g;
      float x0v = (float)b2h((u16)(x0p[q>>1] >> (16*(q&1))));
      float v = x0v + diag8[row]*acc0[q] + acc1[q] + bias_c;
      xh[row*XP + ccol] = h2b((_Float16)v);
    }
    __syncthreads();   // (2) xh ready; h1t reads drained
  }

  // ---- LayerNorm + store (reads f16 xh), 16 waves
  float ga = gamma[lane], g2 = gamma[64+lane];
  float ba = beta[lane],  b2f = beta[64+lane];
  #pragma unroll 1
  for (int i = 0; i < 8; ++i) {
    int r = wid + 16*i;            // wave-uniform, 0..127
    if (r >= ROWS) continue;
    int grow = grow0 + r;
    if (grow >= totRows) continue;
    float xa = (float)b2h(xh[r*XP + lane]);
    float xc = (float)b2h(xh[r*XP + 64 + lane]);
    float mu = wred(xa + xc) * (1.f/128.f);
    float da = xa - mu, dc = xc - mu;
    float vs = wred(da*da + dc*dc) * (1.f/128.f);
    float rs = rsqrtf(vs + 1e-10f);
    size_t ob = (size_t)grow*CC;
    out[ob + lane]      = da*rs*ga + ba;
    out[ob + 64 + lane] = dc*rs*g2 + b2f;
  }
}

extern "C" void kernel_launch(void* const* d_in, const int* in_sizes, int n_in,
                              void* d_out, int out_size, void* d_ws, size_t ws_size,
                              hipStream_t stream) {
  const float* x   = (const float*)d_in[0];
  const float* x0  = (const float*)d_in[1];
  const float* adj = (const float*)d_in[2];
  const float* W0  = (const float*)d_in[3];
  const float* W1  = (const float*)d_in[4];
  const float* bv  = (const float*)d_in[5];
  const float* ga  = (const float*)d_in[6];
  const float* be  = (const float*)d_in[7];
  u16* wsH   = (u16*)d_ws;                      // [2][128][128] f16 = 65536 B
  u16* amixf = (u16*)((char*)d_ws + 65536);     // [4][4][2][32][8] f16 = 16384 B
  int totRows = in_sizes[0] / CC;
  int nBatch  = totRows / JJ;
  int grid    = (nBatch + BB - 1) / BB;
  wprep<<<dim3(2), dim3(256), 0, stream>>>(W0, W1, adj, wsH, amixf);
  hipFuncSetAttribute((const void*)gconv_fused,
                      hipFuncAttributeMaxDynamicSharedMemorySize, LDS_BYTES);
  gconv_fused<<<dim3(grid), dim3(NT), LDS_BYTES, stream>>>(
      x, x0, adj, wsH, amixf, bv, ga, be, (float*)d_out, totRows);
}